// Round 8
// baseline (844.333 us; speedup 1.0000x reference)
//
#include <hip/hip_runtime.h>
#include <hip/hip_bf16.h>

// GAT: N=50000, E=850000, HID=128, HEADS=8, DH=16, LAYERS=2.
// R8: full-row aggregate (wave per node, 64 lanes = 128 features, scalar csr
//     loads, 4 line-requests/edge -> L2-miss-fill-bound ~2.9 TB/s), and
//     two-phase bucketed CSR scatter (dense line fill, kills write amp).
//     h full-row bf16 [node][128]; alphas interleaved [node][8].

typedef __attribute__((ext_vector_type(8))) short short8;   // 8 bf16 = 4 VGPRs
typedef __attribute__((ext_vector_type(4))) float floatx4;

__device__ __forceinline__ unsigned f2u(float f) { return __float_as_uint(f); }
__device__ __forceinline__ float u2f(unsigned u) { return __uint_as_float(u); }
__device__ __forceinline__ unsigned short f2bf_rne(float x) {
    unsigned u = f2u(x);
    unsigned r = (u + 0x7FFF + ((u >> 16) & 1)) >> 16;
    return (unsigned short)r;
}
__device__ __forceinline__ float bf2f(unsigned short b) { return u2f(((unsigned)b) << 16); }

// ---------------- CSR build ----------------

__global__ void hist_kernel(const int* __restrict__ row, int* __restrict__ deg, int E) {
    int e = blockIdx.x * 256 + threadIdx.x;
    if (e < E) atomicAdd(&deg[row[e]], 1);
}

__global__ void blocksum_kernel(const int* __restrict__ deg, int* __restrict__ bsum, int n) {
    __shared__ int sd[512];
    int t = threadIdx.x;
    int idx = blockIdx.x * 512 + t;
    sd[t] = (idx < n) ? deg[idx] : 0;
    __syncthreads();
    for (int off = 256; off; off >>= 1) {
        if (t < off) sd[t] += sd[t + off];
        __syncthreads();
    }
    if (t == 0) bsum[blockIdx.x] = sd[0];
}

__global__ void scanbsum_kernel(const int* __restrict__ bsum, int* __restrict__ boff,
                                int nb, int* __restrict__ rowptr, int n) {
    __shared__ int sd[128];
    int t = threadIdx.x;
    int v = (t < nb) ? bsum[t] : 0;
    sd[t] = v;
    __syncthreads();
    for (int off = 1; off < 128; off <<= 1) {
        int add = (t >= off) ? sd[t - off] : 0;
        __syncthreads();
        sd[t] += add;
        __syncthreads();
    }
    if (t < nb) boff[t] = sd[t] - v;
    if (t == nb - 1) rowptr[n] = sd[t];
}

__global__ void scanfinal_kernel(const int* __restrict__ deg, const int* __restrict__ boff,
                                 int* __restrict__ rowptr, int* __restrict__ cursor, int n) {
    __shared__ int sd[512];
    int t = threadIdx.x;
    int idx = blockIdx.x * 512 + t;
    int v = (idx < n) ? deg[idx] : 0;
    sd[t] = v;
    __syncthreads();
    for (int off = 1; off < 512; off <<= 1) {
        int add = (t >= off) ? sd[t - off] : 0;
        __syncthreads();
        sd[t] += add;
        __syncthreads();
    }
    if (idx < n) {
        int excl = sd[t] - v + boff[blockIdx.x];
        rowptr[idx] = excl;
        cursor[idx] = excl;
    }
}

// bucket cursors: bucket b = rows [b*256,(b+1)*256), base = rowptr[b*256]
__global__ void bcur_init_kernel(const int* __restrict__ rowptr, int* __restrict__ bcur,
                                 int nbkt) {
    int b = blockIdx.x * 256 + threadIdx.x;
    if (b < nbkt) bcur[b] = rowptr[b * 256];
}

// pass A: bin edges by row>>8; per-bucket sequential cursor -> dense line fill
__global__ void scatterA_kernel(const int* __restrict__ row, const int* __restrict__ colv,
                                const float* __restrict__ ev, int* __restrict__ bcur,
                                int2* __restrict__ tmp, int E) {
    int e = blockIdx.x * 256 + threadIdx.x;
    if (e < E) {
        int r = row[e];
        int slot = atomicAdd(&bcur[r >> 8], 1);
        // N=50000 < 65536: row and col each fit in 16 bits
        tmp[slot] = make_int2((r << 16) | colv[e], __float_as_int(ev[e]));
    }
}

// pass B: place within 256-node bucket region (~35KB, L2-resident writes)
__global__ void scatterB_kernel(const int2* __restrict__ tmp, int* __restrict__ cursor,
                                int2* __restrict__ csr, int E) {
    int e = blockIdx.x * 256 + threadIdx.x;
    if (e < E) {
        int2 t = tmp[e];
        unsigned rc = (unsigned)t.x;
        int r = rc >> 16;
        int c = rc & 0xFFFF;
        int slot = atomicAdd(&cursor[r], 1);
        csr[slot] = make_int2(c, t.y);
    }
}

// ---------------- W pack: fp32 -> split-bf16 B-fragment layout ----------------

__global__ void pack_kernel(const float* __restrict__ encW, const float* __restrict__ Wstack,
                            short8* __restrict__ Wh, short8* __restrict__ Wl) {
    int idx = blockIdx.x * 256 + threadIdx.x;
    if (idx >= 3 * 2048) return;
    int mat = idx >> 11;
    int r = idx & 2047;
    int lane = r & 63;
    int tile = r >> 6;            // ct*4 + kt
    int ct = tile >> 2, kt = tile & 3;
    int ncol = ct * 16 + (lane & 15);
    int k0 = kt * 32 + ((lane >> 4) * 8);
    short8 hv, lv;
#pragma unroll
    for (int j = 0; j < 8; ++j) {
        int k = k0 + j;
        float w = (mat == 0)
            ? encW[k * 128 + ncol]
            : Wstack[(mat - 1) * 16384 + (ncol >> 4) * 2048 + k * 16 + (ncol & 15)];
        unsigned u = f2u(w);
        hv[j] = (short)(u >> 16);
        float hf = u2f(u & 0xFFFF0000u);
        float l = w - hf;
        lv[j] = (short)(f2u(l) >> 16);
    }
    Wh[idx] = hv;
    Wl[idx] = lv;
}

// ---------------- MFMA GEMM ----------------
// flags: bit0 = add bias, bit1 = alpha epilogue ([node*8+head] interleaved),
//        bit2 = store C as bf16 full-row [node][128].

__global__ __launch_bounds__(256) void
gemm_mfma(const float* __restrict__ A, const short8* __restrict__ Bh,
          const short8* __restrict__ Bl, const float* __restrict__ bias,
          const float* __restrict__ avec, float* __restrict__ Cf,
          unsigned short* __restrict__ Cbf,
          float* __restrict__ asrc, float* __restrict__ adst, int n, int flags) {
    int wave = threadIdx.x >> 6;
    int lane = threadIdx.x & 63;
    int q = lane >> 4;
    int col = lane & 15;
    int n0w = blockIdx.x * 64 + wave * 16;

    int arow = min(n0w + col, n - 1);
    const float* Arow = A + (size_t)arow * 128;
    int kb = q * 8;
    short8 Ah[4], Al[4];
#pragma unroll
    for (int kt = 0; kt < 4; ++kt) {
        float4 f0 = *(const float4*)(Arow + kt * 32 + kb);
        float4 f1 = *(const float4*)(Arow + kt * 32 + kb + 4);
        float fv[8] = {f0.x, f0.y, f0.z, f0.w, f1.x, f1.y, f1.z, f1.w};
#pragma unroll
        for (int j = 0; j < 8; ++j) {
            unsigned u = f2u(fv[j]);
            Ah[kt][j] = (short)(u >> 16);
            float hf = u2f(u & 0xFFFF0000u);
            float l = fv[j] - hf;
            Al[kt][j] = (short)(f2u(l) >> 16);
        }
    }

    int nbase = n0w + q * 4;
#pragma unroll
    for (int ct = 0; ct < 8; ++ct) {
        short8 bh[4], bl[4];
#pragma unroll
        for (int kt = 0; kt < 4; ++kt) {
            bh[kt] = Bh[(ct * 4 + kt) * 64 + lane];
            bl[kt] = Bl[(ct * 4 + kt) * 64 + lane];
        }
        float bv = (flags & 1) ? bias[ct * 16 + col] : 0.f;
        floatx4 acc = {bv, bv, bv, bv};
#pragma unroll
        for (int kt = 0; kt < 4; ++kt) {
            acc = __builtin_amdgcn_mfma_f32_16x16x32_bf16(Ah[kt], bh[kt], acc, 0, 0, 0);
            acc = __builtin_amdgcn_mfma_f32_16x16x32_bf16(Al[kt], bh[kt], acc, 0, 0, 0);
            acc = __builtin_amdgcn_mfma_f32_16x16x32_bf16(Ah[kt], bl[kt], acc, 0, 0, 0);
        }
#pragma unroll
        for (int reg = 0; reg < 4; ++reg) {
            int node = nbase + reg;
            if (node < n) {
                if (flags & 4)
                    Cbf[(size_t)node * 128 + ct * 16 + col] = f2bf_rne(acc[reg]);
                else
                    Cf[(size_t)node * 128 + ct * 16 + col] = acc[reg];
            }
        }
        if (flags & 2) {
            float a_s = avec[ct * 32 + col];
            float a_d = avec[ct * 32 + 16 + col];
#pragma unroll
            for (int reg = 0; reg < 4; ++reg) {
                float ps = acc[reg] * a_s;
                float pd = acc[reg] * a_d;
#pragma unroll
                for (int off = 8; off; off >>= 1) {
                    ps += __shfl_down(ps, off, 16);
                    pd += __shfl_down(pd, off, 16);
                }
                int node = nbase + reg;
                if (col == 0 && node < n) {
                    asrc[(size_t)node * 8 + ct] = ps;
                    adst[(size_t)node * 8 + ct] = pd;
                }
            }
        }
    }
}

// ---------------- aggregate: full-row, wave per node ----------------
// 64 lanes, lane l owns features 2l,2l+1 (ushort2 h load: 256B/edge = 2 lines).
// head = l>>3. csr loads are wave-uniform -> scalar path via readfirstlane.
// Per edge: ~4 line-requests total; bound = L2-miss fill (~2.9 TB/s).

__global__ __launch_bounds__(256) void
aggregate_kernel(const int* __restrict__ rowptr, const int2* __restrict__ csr,
                 const ushort2* __restrict__ hrow,
                 const float* __restrict__ asrc, const float* __restrict__ adst,
                 const float* __restrict__ resid, float* __restrict__ out,
                 int mode, int n) {
    int wave = threadIdx.x >> 6;
    int lane = threadIdx.x & 63;
    int nd = blockIdx.x * 4 + wave;
    if (nd >= n) return;
    nd = __builtin_amdgcn_readfirstlane(nd);
    int hd = lane >> 3;

    float as = asrc[(size_t)nd * 8 + hd];
    int s0 = __builtin_amdgcn_readfirstlane(rowptr[nd]);
    int e0 = __builtin_amdgcn_readfirstlane(rowptr[nd + 1]);

    float acc0 = 0.f, acc1 = 0.f, wsum = 0.f;
    int j = s0;
    for (; j + 2 <= e0; j += 2) {
        int2 cv0 = csr[j];
        int2 cv1 = csr[j + 1];
        int c0 = __builtin_amdgcn_readfirstlane(cv0.x);
        int c1 = __builtin_amdgcn_readfirstlane(cv1.x);
        float ad0 = adst[(size_t)c0 * 8 + hd];
        float ad1 = adst[(size_t)c1 * 8 + hd];
        ushort2 h0 = hrow[(size_t)c0 * 64 + lane];
        ushort2 h1 = hrow[(size_t)c1 * 64 + lane];
        float lg0 = __int_as_float(cv0.y) * (as + ad0);
        float lg1 = __int_as_float(cv1.y) * (as + ad1);
        lg0 = lg0 > 0.f ? lg0 : 0.2f * lg0;
        lg1 = lg1 > 0.f ? lg1 : 0.2f * lg1;
        float w0 = __expf(lg0);
        float w1 = __expf(lg1);
        acc0 += w0 * bf2f(h0.x) + w1 * bf2f(h1.x);
        acc1 += w0 * bf2f(h0.y) + w1 * bf2f(h1.y);
        wsum += w0 + w1;
    }
    if (j < e0) {
        int2 cv = csr[j];
        int c = __builtin_amdgcn_readfirstlane(cv.x);
        float ad = adst[(size_t)c * 8 + hd];
        ushort2 hv = hrow[(size_t)c * 64 + lane];
        float lg = __int_as_float(cv.y) * (as + ad);
        lg = lg > 0.f ? lg : 0.2f * lg;
        float w = __expf(lg);
        acc0 += w * bf2f(hv.x);
        acc1 += w * bf2f(hv.y);
        wsum += w;
    }

    float inv = 1.f / wsum;   // self-loop guarantees wsum > 0
    float o0 = acc0 * inv, o1 = acc1 * inv;
    size_t oi = (size_t)nd * 128 + lane * 2;
    if (mode == 0) {
        o0 = o0 > 0.f ? o0 : expm1f(o0);
        o1 = o1 > 0.f ? o1 : expm1f(o1);
    } else {
        float2 r = *(const float2*)(resid + oi);
        o0 += r.x; o1 += r.y;
    }
    float2 o = {o0, o1};
    *(float2*)(out + oi) = o;
}

// ---------------- launch ----------------

extern "C" void kernel_launch(void* const* d_in, const int* in_sizes, int n_in,
                              void* d_out, int out_size, void* d_ws, size_t ws_size,
                              hipStream_t stream) {
    const int N = in_sizes[0] / 128;
    const int E = in_sizes[2];

    const float* x      = (const float*)d_in[0];
    const int*   eidx   = (const int*)d_in[1];
    const float* ev     = (const float*)d_in[2];
    const float* encW   = (const float*)d_in[3];
    const float* encb   = (const float*)d_in[4];
    const float* Wstack = (const float*)d_in[5];
    const float* astack = (const float*)d_in[6];
    float* out = (float*)d_out;

    const int* row = eidx;
    const int* colv = eidx + E;

    char* p = (char*)d_ws;
    float* xc   = (float*)p; p += (size_t)N * 128 * 4;
    float* xcB  = (float*)p; p += (size_t)N * 128 * 4;
    unsigned short* hrow = (unsigned short*)p; p += (size_t)N * 128 * 2;
    float* asrc = (float*)p; p += (size_t)N * 8 * 4;
    float* adst = (float*)p; p += (size_t)N * 8 * 4;
    short8* Wh  = (short8*)p; p += 3 * 2048 * 16;
    short8* Wl  = (short8*)p; p += 3 * 2048 * 16;
    int* rowptr = (int*)p;   p += (size_t)(N + 1) * 4;
    int* cursor = (int*)p;   p += (size_t)N * 4;
    int* deg    = (int*)p;   p += (size_t)N * 4;
    int* bsum   = (int*)p;   p += 128 * 4;
    int* boff   = (int*)p;   p += 128 * 4;
    int* bcur   = (int*)p;   p += 256 * 4;
    int2* csr   = (int2*)p;  p += (size_t)E * 8;
    int2* tmp   = (int2*)p;  p += (size_t)E * 8;

    const int NB = (N + 511) / 512;
    const int NBKT = (N + 255) / 256;
    const int GB = (N + 63) / 64;
    const int AGB = (N + 3) / 4;

    // --- CSR build (two-phase bucketed scatter) ---
    hipMemsetAsync(deg, 0, (size_t)N * 4, stream);
    hist_kernel<<<(E + 255) / 256, 256, 0, stream>>>(row, deg, E);
    blocksum_kernel<<<NB, 512, 0, stream>>>(deg, bsum, N);
    scanbsum_kernel<<<1, 128, 0, stream>>>(bsum, boff, NB, rowptr, N);
    scanfinal_kernel<<<NB, 512, 0, stream>>>(deg, boff, rowptr, cursor, N);
    bcur_init_kernel<<<1, 256, 0, stream>>>(rowptr, bcur, NBKT);
    scatterA_kernel<<<(E + 255) / 256, 256, 0, stream>>>(row, colv, ev, bcur, tmp, E);
    scatterB_kernel<<<(E + 255) / 256, 256, 0, stream>>>(tmp, cursor, csr, E);

    // --- pack weights ---
    pack_kernel<<<24, 256, 0, stream>>>(encW, Wstack, Wh, Wl);

    // --- encoder: xc = x @ encW + b (fp32 full layout) ---
    gemm_mfma<<<GB, 256, 0, stream>>>(x, Wh, Wl, encb, nullptr, xc, nullptr,
                                      nullptr, nullptr, N, 1);

    // --- layer 0 ---
    gemm_mfma<<<GB, 256, 0, stream>>>(xc, Wh + 2048, Wl + 2048, nullptr, astack,
                                      nullptr, hrow, asrc, adst, N, 2 | 4);
    aggregate_kernel<<<AGB, 256, 0, stream>>>(rowptr, csr, (const ushort2*)hrow,
                                              asrc, adst, nullptr, xcB, 0, N);

    // --- layer 1 ---
    gemm_mfma<<<GB, 256, 0, stream>>>(xcB, Wh + 4096, Wl + 4096, nullptr, astack + 256,
                                      nullptr, hrow, asrc, adst, N, 2 | 4);
    aggregate_kernel<<<AGB, 256, 0, stream>>>(rowptr, csr, (const ushort2*)hrow,
                                              asrc, adst, xcB, out, 1, N);
}

// Round 9
// 487.999 us; speedup vs baseline: 1.7302x; 1.7302x over previous
//
#include <hip/hip_runtime.h>
#include <hip/hip_bf16.h>

// GAT: N=50000, E=850000, HID=128, HEADS=8, DH=16, LAYERS=2.
// R9: scatter reverted to per-node-cursor form (R8's 196-bucket scatter
//     serialized on bucket counters: 4300 serial atomics x 125ns = 534us).
//     Aggregate = 4 slices x 32 features: slice h (3.2MB) + adst (1.6MB)
//     ~L2-resident per XCD (slice = blockIdx&3 -> XCD {s,s+4}); wave =
//     node x slice, half-waves take alternate edges (2-way divergence).

typedef __attribute__((ext_vector_type(8))) short short8;   // 8 bf16 = 4 VGPRs
typedef __attribute__((ext_vector_type(4))) float floatx4;

__device__ __forceinline__ unsigned f2u(float f) { return __float_as_uint(f); }
__device__ __forceinline__ float u2f(unsigned u) { return __uint_as_float(u); }
__device__ __forceinline__ unsigned short f2bf_rne(float x) {
    unsigned u = f2u(x);
    unsigned r = (u + 0x7FFF + ((u >> 16) & 1)) >> 16;
    return (unsigned short)r;
}
__device__ __forceinline__ float bf2f(unsigned short b) { return u2f(((unsigned)b) << 16); }

// ---------------- CSR build ----------------

__global__ void hist_kernel(const int* __restrict__ row, int* __restrict__ deg, int E) {
    int e = blockIdx.x * 256 + threadIdx.x;
    if (e < E) atomicAdd(&deg[row[e]], 1);
}

__global__ void blocksum_kernel(const int* __restrict__ deg, int* __restrict__ bsum, int n) {
    __shared__ int sd[512];
    int t = threadIdx.x;
    int idx = blockIdx.x * 512 + t;
    sd[t] = (idx < n) ? deg[idx] : 0;
    __syncthreads();
    for (int off = 256; off; off >>= 1) {
        if (t < off) sd[t] += sd[t + off];
        __syncthreads();
    }
    if (t == 0) bsum[blockIdx.x] = sd[0];
}

__global__ void scanbsum_kernel(const int* __restrict__ bsum, int* __restrict__ boff,
                                int nb, int* __restrict__ rowptr, int n) {
    __shared__ int sd[128];
    int t = threadIdx.x;
    int v = (t < nb) ? bsum[t] : 0;
    sd[t] = v;
    __syncthreads();
    for (int off = 1; off < 128; off <<= 1) {
        int add = (t >= off) ? sd[t - off] : 0;
        __syncthreads();
        sd[t] += add;
        __syncthreads();
    }
    if (t < nb) boff[t] = sd[t] - v;
    if (t == nb - 1) rowptr[n] = sd[t];
}

__global__ void scanfinal_kernel(const int* __restrict__ deg, const int* __restrict__ boff,
                                 int* __restrict__ rowptr, int* __restrict__ cursor, int n) {
    __shared__ int sd[512];
    int t = threadIdx.x;
    int idx = blockIdx.x * 512 + t;
    int v = (idx < n) ? deg[idx] : 0;
    sd[t] = v;
    __syncthreads();
    for (int off = 1; off < 512; off <<= 1) {
        int add = (t >= off) ? sd[t - off] : 0;
        __syncthreads();
        sd[t] += add;
        __syncthreads();
    }
    if (idx < n) {
        int excl = sd[t] - v + boff[blockIdx.x];
        rowptr[idx] = excl;
        cursor[idx] = excl;
    }
}

__global__ void scatter_kernel(const int* __restrict__ row, const int* __restrict__ colv,
                               const float* __restrict__ ev, int* __restrict__ cursor,
                               int2* __restrict__ csr, int E) {
    int e = blockIdx.x * 256 + threadIdx.x;
    if (e < E) {
        int r = row[e];
        int slot = atomicAdd(&cursor[r], 1);
        csr[slot] = make_int2(colv[e], __float_as_int(ev[e]));
    }
}

// ---------------- W pack: fp32 -> split-bf16 B-fragment layout ----------------

__global__ void pack_kernel(const float* __restrict__ encW, const float* __restrict__ Wstack,
                            short8* __restrict__ Wh, short8* __restrict__ Wl) {
    int idx = blockIdx.x * 256 + threadIdx.x;
    if (idx >= 3 * 2048) return;
    int mat = idx >> 11;
    int r = idx & 2047;
    int lane = r & 63;
    int tile = r >> 6;            // ct*4 + kt
    int ct = tile >> 2, kt = tile & 3;
    int ncol = ct * 16 + (lane & 15);
    int k0 = kt * 32 + ((lane >> 4) * 8);
    short8 hv, lv;
#pragma unroll
    for (int j = 0; j < 8; ++j) {
        int k = k0 + j;
        float w = (mat == 0)
            ? encW[k * 128 + ncol]
            : Wstack[(mat - 1) * 16384 + (ncol >> 4) * 2048 + k * 16 + (ncol & 15)];
        unsigned u = f2u(w);
        hv[j] = (short)(u >> 16);
        float hf = u2f(u & 0xFFFF0000u);
        float l = w - hf;
        lv[j] = (short)(f2u(l) >> 16);
    }
    Wh[idx] = hv;
    Wl[idx] = lv;
}

// ---------------- MFMA GEMM ----------------
// flags: bit0 = add bias, bit1 = alpha epilogue ([node*8+head] interleaved),
//        bit2 = store C as bf16 in 4-slice layout h[s][node][32].

__global__ __launch_bounds__(256) void
gemm_mfma(const float* __restrict__ A, const short8* __restrict__ Bh,
          const short8* __restrict__ Bl, const float* __restrict__ bias,
          const float* __restrict__ avec, float* __restrict__ Cf,
          unsigned short* __restrict__ Cbf,
          float* __restrict__ asrc, float* __restrict__ adst, int n, int flags) {
    int wave = threadIdx.x >> 6;
    int lane = threadIdx.x & 63;
    int q = lane >> 4;
    int col = lane & 15;
    int n0w = blockIdx.x * 64 + wave * 16;

    int arow = min(n0w + col, n - 1);
    const float* Arow = A + (size_t)arow * 128;
    int kb = q * 8;
    short8 Ah[4], Al[4];
#pragma unroll
    for (int kt = 0; kt < 4; ++kt) {
        float4 f0 = *(const float4*)(Arow + kt * 32 + kb);
        float4 f1 = *(const float4*)(Arow + kt * 32 + kb + 4);
        float fv[8] = {f0.x, f0.y, f0.z, f0.w, f1.x, f1.y, f1.z, f1.w};
#pragma unroll
        for (int j = 0; j < 8; ++j) {
            unsigned u = f2u(fv[j]);
            Ah[kt][j] = (short)(u >> 16);
            float hf = u2f(u & 0xFFFF0000u);
            float l = fv[j] - hf;
            Al[kt][j] = (short)(f2u(l) >> 16);
        }
    }

    int nbase = n0w + q * 4;
#pragma unroll
    for (int ct = 0; ct < 8; ++ct) {
        short8 bh[4], bl[4];
#pragma unroll
        for (int kt = 0; kt < 4; ++kt) {
            bh[kt] = Bh[(ct * 4 + kt) * 64 + lane];
            bl[kt] = Bl[(ct * 4 + kt) * 64 + lane];
        }
        float bv = (flags & 1) ? bias[ct * 16 + col] : 0.f;
        floatx4 acc = {bv, bv, bv, bv};
#pragma unroll
        for (int kt = 0; kt < 4; ++kt) {
            acc = __builtin_amdgcn_mfma_f32_16x16x32_bf16(Ah[kt], bh[kt], acc, 0, 0, 0);
            acc = __builtin_amdgcn_mfma_f32_16x16x32_bf16(Al[kt], bh[kt], acc, 0, 0, 0);
            acc = __builtin_amdgcn_mfma_f32_16x16x32_bf16(Ah[kt], bl[kt], acc, 0, 0, 0);
        }
#pragma unroll
        for (int reg = 0; reg < 4; ++reg) {
            int node = nbase + reg;
            if (node < n) {
                if (flags & 4)
                    Cbf[(size_t)(ct >> 1) * n * 32 + (size_t)node * 32 + (ct & 1) * 16 + col] =
                        f2bf_rne(acc[reg]);
                else
                    Cf[(size_t)node * 128 + ct * 16 + col] = acc[reg];
            }
        }
        if (flags & 2) {
            float a_s = avec[ct * 32 + col];
            float a_d = avec[ct * 32 + 16 + col];
#pragma unroll
            for (int reg = 0; reg < 4; ++reg) {
                float ps = acc[reg] * a_s;
                float pd = acc[reg] * a_d;
#pragma unroll
                for (int off = 8; off; off >>= 1) {
                    ps += __shfl_down(ps, off, 16);
                    pd += __shfl_down(pd, off, 16);
                }
                int node = nbase + reg;
                if (col == 0 && node < n) {
                    asrc[(size_t)node * 8 + ct] = ps;
                    adst[(size_t)node * 8 + ct] = pd;
                }
            }
        }
    }
}

// ---------------- aggregate: 4 slices x 32 features, wave per (node,slice) ----------------
// blockIdx: slice = &3 (-> XCD {s, s+4} under round-robin; perf-only),
// node chunk = >>2, 4 waves = 4 nodes. Lane = half*32 + fl: half-waves take
// alternate edges; lane owns 1 feature (2B). head = slice*2 + (fl>>4).
// x2 unrolled: 4 edges in flight. shfl_xor(32) combines halves.

__global__ __launch_bounds__(256) void
aggregate_kernel(const int* __restrict__ rowptr, const int2* __restrict__ csr,
                 const unsigned short* __restrict__ hsl,
                 const float* __restrict__ asrc, const float* __restrict__ adst,
                 const float* __restrict__ resid, float* __restrict__ out,
                 int mode, int n) {
    int wave = threadIdx.x >> 6;
    int lane = threadIdx.x & 63;
    int slice = blockIdx.x & 3;
    int nd = (blockIdx.x >> 2) * 4 + wave;
    if (nd >= n) return;
    int half = lane >> 5;
    int fl = lane & 31;
    int head = slice * 2 + (fl >> 4);

    const unsigned short* hs = hsl + (size_t)slice * n * 32;
    float as = asrc[(size_t)nd * 8 + head];
    int s0 = rowptr[nd], e0 = rowptr[nd + 1];

    float acc = 0.f, wsum = 0.f;
    for (int j = s0; j < e0; j += 4) {
        int j0 = j + half;
        int j1 = j + 2 + half;
        bool a0 = j0 < e0, a1 = j1 < e0;
        int2 cv0 = csr[a0 ? j0 : s0];
        int2 cv1 = csr[a1 ? j1 : s0];
        float ad0 = adst[(size_t)cv0.x * 8 + head];
        float ad1 = adst[(size_t)cv1.x * 8 + head];
        unsigned short h0 = hs[(size_t)cv0.x * 32 + fl];
        unsigned short h1 = hs[(size_t)cv1.x * 32 + fl];
        float lg0 = __int_as_float(cv0.y) * (as + ad0);
        float lg1 = __int_as_float(cv1.y) * (as + ad1);
        lg0 = lg0 > 0.f ? lg0 : 0.2f * lg0;
        lg1 = lg1 > 0.f ? lg1 : 0.2f * lg1;
        float w0 = a0 ? __expf(lg0) : 0.f;
        float w1 = a1 ? __expf(lg1) : 0.f;
        acc += w0 * bf2f(h0) + w1 * bf2f(h1);
        wsum += w0 + w1;
    }
    acc += __shfl_xor(acc, 32, 64);
    wsum += __shfl_xor(wsum, 32, 64);

    if (lane < 32) {
        float o = acc / wsum;   // self-loop guarantees wsum > 0
        size_t oi = (size_t)nd * 128 + slice * 32 + fl;
        if (mode == 0) {
            o = o > 0.f ? o : expm1f(o);
        } else {
            o += resid[oi];
        }
        out[oi] = o;
    }
}

// ---------------- launch ----------------

extern "C" void kernel_launch(void* const* d_in, const int* in_sizes, int n_in,
                              void* d_out, int out_size, void* d_ws, size_t ws_size,
                              hipStream_t stream) {
    const int N = in_sizes[0] / 128;
    const int E = in_sizes[2];

    const float* x      = (const float*)d_in[0];
    const int*   eidx   = (const int*)d_in[1];
    const float* ev     = (const float*)d_in[2];
    const float* encW   = (const float*)d_in[3];
    const float* encb   = (const float*)d_in[4];
    const float* Wstack = (const float*)d_in[5];
    const float* astack = (const float*)d_in[6];
    float* out = (float*)d_out;

    const int* row = eidx;
    const int* colv = eidx + E;

    char* p = (char*)d_ws;
    float* xc   = (float*)p; p += (size_t)N * 128 * 4;
    float* xcB  = (float*)p; p += (size_t)N * 128 * 4;
    unsigned short* hsl = (unsigned short*)p; p += (size_t)N * 128 * 2;
    float* asrc = (float*)p; p += (size_t)N * 8 * 4;
    float* adst = (float*)p; p += (size_t)N * 8 * 4;
    short8* Wh  = (short8*)p; p += 3 * 2048 * 16;
    short8* Wl  = (short8*)p; p += 3 * 2048 * 16;
    int* rowptr = (int*)p;   p += (size_t)(N + 1) * 4;
    int* cursor = (int*)p;   p += (size_t)N * 4;
    int* deg    = (int*)p;   p += (size_t)N * 4;
    int* bsum   = (int*)p;   p += 128 * 4;
    int* boff   = (int*)p;   p += 128 * 4;
    int2* csr   = (int2*)p;  p += (size_t)E * 8;

    const int NB = (N + 511) / 512;
    const int GB = (N + 63) / 64;
    const int AB = ((N + 3) / 4) * 4;   // aggregate: chunk*4 + slice

    // --- CSR build ---
    hipMemsetAsync(deg, 0, (size_t)N * 4, stream);
    hist_kernel<<<(E + 255) / 256, 256, 0, stream>>>(row, deg, E);
    blocksum_kernel<<<NB, 512, 0, stream>>>(deg, bsum, N);
    scanbsum_kernel<<<1, 128, 0, stream>>>(bsum, boff, NB, rowptr, N);
    scanfinal_kernel<<<NB, 512, 0, stream>>>(deg, boff, rowptr, cursor, N);
    scatter_kernel<<<(E + 255) / 256, 256, 0, stream>>>(row, colv, ev, cursor, csr, E);

    // --- pack weights ---
    pack_kernel<<<24, 256, 0, stream>>>(encW, Wstack, Wh, Wl);

    // --- encoder: xc = x @ encW + b (fp32 full layout) ---
    gemm_mfma<<<GB, 256, 0, stream>>>(x, Wh, Wl, encb, nullptr, xc, nullptr,
                                      nullptr, nullptr, N, 1);

    // --- layer 0 ---
    gemm_mfma<<<GB, 256, 0, stream>>>(xc, Wh + 2048, Wl + 2048, nullptr, astack,
                                      nullptr, hsl, asrc, adst, N, 2 | 4);
    aggregate_kernel<<<AB, 256, 0, stream>>>(rowptr, csr, hsl, asrc, adst,
                                             nullptr, xcB, 0, N);

    // --- layer 1 ---
    gemm_mfma<<<GB, 256, 0, stream>>>(xcB, Wh + 4096, Wl + 4096, nullptr, astack + 256,
                                      nullptr, hsl, asrc, adst, N, 2 | 4);
    aggregate_kernel<<<AB, 256, 0, stream>>>(rowptr, csr, hsl, asrc, adst,
                                             xcB, out, 1, N);
}